// Round 6
// baseline (22044.589 us; speedup 1.0000x reference)
//
#include <hip/hip_runtime.h>
#include <stdint.h>

#define NB 256      // batch
#define TSEQ 1024   // sequence length
#define TT_MAX 64

typedef _Float16 f16;
typedef _Float16 h2 __attribute__((ext_vector_type(2)));

static __device__ __forceinline__ uint32_t pkh2(float a, float b) {
  h2 v; v[0] = (f16)a; v[1] = (f16)b;
  return __builtin_bit_cast(uint32_t, v);
}

#if __has_builtin(__builtin_amdgcn_fdot2)
static __device__ __forceinline__ float dot2u(uint32_t w, uint32_t h, float c) {
  return __builtin_amdgcn_fdot2(__builtin_bit_cast(h2, w), __builtin_bit_cast(h2, h), c, false);
}
#else
static __device__ __forceinline__ float dot2u(uint32_t w, uint32_t h, float c) {
  h2 a = __builtin_bit_cast(h2, w), b = __builtin_bit_cast(h2, h);
  return c + (float)a[0] * (float)b[0] + (float)a[1] * (float)b[1];
}
#endif

#if __has_builtin(__builtin_amdgcn_rcpf)
#define RCPF(x) __builtin_amdgcn_rcpf(x)
#else
#define RCPF(x) (1.0f / (x))
#endif

static __device__ __forceinline__ float sigm(float x) {
  return RCPF(1.0f + exp2f(-1.44269504f * x));
}
static __device__ __forceinline__ float tanh_f(float x) {
  return 1.0f - 2.0f * RCPF(1.0f + exp2f(2.88539008f * x));
}

// ---------------------------------------------------------------------------
// Precompute kernel: gi_x'[tloc][b][768] = W_ih[:, :64] @ x_t + b_ih (+ b_hh for r,z rows)
//                    zx'  [tloc][b][64]  = enc{mu,sigma}_W[:, :64] @ x_t + bias
// ---------------------------------------------------------------------------
__global__ __launch_bounds__(256, 2) void vrnn_pre(
    const float* __restrict__ x, const float* __restrict__ W_ih,
    const float* __restrict__ b_ih, const float* __restrict__ b_hh,
    const float* __restrict__ emW, const float* __restrict__ emb,
    const float* __restrict__ esW, const float* __restrict__ esb,
    f16* __restrict__ gix, f16* __restrict__ zx,
    int chunk_t0, int TT, int nTT)
{
  const int tid = threadIdx.x;
  const int b  = blockIdx.x / nTT;
  const int tt = blockIdx.x % nTT;
  const int tloc0 = tt * TT;

  // x-part rows of W_ih for the thread's gate triple (j, j+256, j+512), f16-packed
  uint32_t wx[3][32];
  float bias[3];
  #pragma unroll
  for (int rr = 0; rr < 3; ++rr) {
    int j = tid + rr * 256;
    const float4* wr = (const float4*)(W_ih + (size_t)j * 96);
    #pragma unroll
    for (int p4 = 0; p4 < 16; ++p4) {
      float4 v = wr[p4];
      wx[rr][2 * p4]     = pkh2(v.x, v.y);
      wx[rr][2 * p4 + 1] = pkh2(v.z, v.w);
    }
    bias[rr] = b_ih[j] + (rr < 2 ? b_hh[j] : 0.0f);  // fold b_hh into r,z rows only
  }
  uint32_t we[32]; float ebias = 0.0f;
  if (tid < 64) {
    const float* src = (tid < 32) ? (emW + (size_t)tid * 320)
                                  : (esW + (size_t)(tid - 32) * 320);
    #pragma unroll
    for (int p = 0; p < 32; ++p) we[p] = pkh2(src[2 * p], src[2 * p + 1]);
    ebias = (tid < 32) ? emb[tid] : esb[tid - 32];
  }

  __shared__ uint32_t xs[TT_MAX * 32];   // x tile, f16-packed
  for (int idx = tid; idx < TT * 32; idx += 256) {
    int tl = idx >> 5, pk = idx & 31;
    size_t base = ((size_t)b * TSEQ + (chunk_t0 + tloc0 + tl)) * 64 + 2 * pk;
    xs[idx] = pkh2(x[base], x[base + 1]);
  }
  __syncthreads();

  for (int tl = 0; tl < TT; ++tl) {
    float a0 = bias[0], a1 = bias[1], a2 = bias[2];
    #pragma unroll
    for (int p = 0; p < 32; ++p) {
      uint32_t u = xs[tl * 32 + p];
      a0 = dot2u(wx[0][p], u, a0);
      a1 = dot2u(wx[1][p], u, a1);
      a2 = dot2u(wx[2][p], u, a2);
    }
    size_t ob = (size_t)(tloc0 + tl) * NB + b;
    f16* g = gix + ob * 768;
    g[tid] = (f16)a0; g[tid + 256] = (f16)a1; g[tid + 512] = (f16)a2;
    if (tid < 64) {
      float a3 = ebias;
      #pragma unroll
      for (int p = 0; p < 32; ++p) a3 = dot2u(we[p], xs[tl * 32 + p], a3);
      zx[ob * 64 + tid] = (f16)a3;
    }
  }
}

// ---------------------------------------------------------------------------
// Recurrent kernel: one block per batch element, 512 threads (8 waves).
// Thread pair (2i, 2i+1) owns rows (i, i+256, i+512) of W_hh split by k-half.
// NOTE: __launch_bounds__(512) (NOT (512,2)): a 512-thread block needs 2
// waves/SIMD so HW caps VGPRs at 256; declaring min-2-blocks/CU capped at 128
// and spilled the 192-VGPR W_hh array to scratch (R1: VALUBusy 5%, 4.4 GB HBM).
// ---------------------------------------------------------------------------
__global__ __launch_bounds__(512) void vrnn_rec(
    const f16* __restrict__ gix, const f16* __restrict__ zx,
    const float* __restrict__ eps,
    const float* __restrict__ W_hh, const float* __restrict__ W_ih,
    const float* __restrict__ emW, const float* __restrict__ esW,
    const float* __restrict__ b_hh,
    float* __restrict__ hws, float* __restrict__ out,
    int t0, int Tlen, int first, int last)
{
  const int tid  = threadIdx.x;
  const int b    = blockIdx.x;
  const int hrow = tid >> 1;      // 0..255 : hidden index / gate-row base
  const int half = tid & 1;       // k-half of the contraction

  // ---- W_hh k-half rows in registers (3 x 64 packed f16 pairs = 192 VGPRs) ----
  uint32_t wh[3][64];
  #pragma unroll
  for (int rr = 0; rr < 3; ++rr) {
    const float4* wr = (const float4*)(W_hh + (size_t)(hrow + rr * 256) * 256 + 128 * half);
    #pragma unroll
    for (int p4 = 0; p4 < 32; ++p4) {
      float4 v = wr[p4];
      wh[rr][2 * p4]     = pkh2(v.x, v.y);
      wh[rr][2 * p4 + 1] = pkh2(v.z, v.w);
    }
  }
  float bhn = b_hh[512 + hrow];   // n-gate hidden bias (kept inside r*(h_n+b))

  // ---- LDS: z-part of W_ih (XOR-swizzled), enc h-part weights (rot-swizzled), state ----
  __shared__ uint32_t wzl[768 * 16];     // 48 KB
  __shared__ uint32_t encw[64 * 128];    // 32 KB
  __shared__ __align__(16) f16 hf[2][256];
  __shared__ float encp[512];
  __shared__ uint32_t zu[16];

  // XOR swizzle: read index is (pz ^ (hrow&15)); the half=0 set (pz<8) and
  // half=1 set (pz>=8) differ in bit 3 -> bank-disjoint -> 2-way (free).
  for (int idx = tid; idx < 768 * 16; idx += 512) {
    int j = idx >> 4, pz = idx & 15;
    wzl[j * 16 + (pz ^ (j & 15))] = pkh2(W_ih[(size_t)j * 96 + 64 + 2 * pz],
                                         W_ih[(size_t)j * 96 + 64 + 2 * pz + 1]);
  }
  for (int idx = tid; idx < 64 * 128; idx += 512) {
    int row = idx >> 7, pc = idx & 127;
    const float* src = (row < 32) ? (emW + (size_t)row * 320 + 64)
                                  : (esW + (size_t)(row - 32) * 320 + 64);
    encw[(row << 7) + ((pc + row) & 127)] = pkh2(src[2 * pc], src[2 * pc + 1]);
  }

  float hm = first ? 0.0f : hws[b * 256 + hrow];
  if (!half) hf[0][hrow] = (f16)hm;
  __syncthreads();

  // ---- stream prefetch for t=0 ----
  const f16* gp0 = gix + (size_t)b * 768;
  float pf_g0 = (float)gp0[hrow], pf_g1 = (float)gp0[hrow + 256], pf_g2 = (float)gp0[hrow + 512];
  float pf_zm = 0.0f, pf_zl = 0.0f, pf_ep = 0.0f;
  if (tid < 32) {
    const f16* zp = zx + (size_t)b * 64;
    pf_zm = (float)zp[tid]; pf_zl = (float)zp[32 + tid];
    pf_ep = eps[((size_t)t0 * NB + b) * 32 + tid];
  }

  const int erow = tid & 63, eq = tid >> 6;      // enc partial assignment
  const uint32_t* encw_r = encw + (erow << 7);
  const int zswz = hrow & 15;

  for (int tl = 0; tl < Tlen; ++tl) {
    const int cur = tl & 1, nxt = cur ^ 1;
    const uint32_t* hu = (const uint32_t*)&hf[cur][0];

    // ---- phase A: encoder h-part partials (16 k-pairs per thread) ----
    float epacc = 0.0f;
    #pragma unroll
    for (int p = 0; p < 16; ++p) {
      int pc = eq * 16 + p;
      epacc = dot2u(encw_r[(pc + erow) & 127], hu[pc], epacc);
    }
    encp[tid] = epacc;
    __syncthreads();  // b1

    // ---- phase B: z (32 threads) || gh (all threads) ----
    if (tid < 32) {
      float mu = pf_zm, lv = pf_zl;
      #pragma unroll
      for (int qq = 0; qq < 8; ++qq) {
        mu += encp[qq * 64 + tid];
        lv += encp[qq * 64 + 32 + tid];
      }
      float z = mu + pf_ep * exp2f(0.72134752f * lv);   // mu + eps*exp(0.5*lv)
      ((f16*)zu)[tid] = (f16)z;
    }
    // gh: 16 x ds_read_b128 broadcast + 192 dot2
    const uint4* hup4 = (const uint4*)(hu + half * 64);
    float g0 = 0.0f, g1 = 0.0f, g2 = 0.0f;
    #pragma unroll
    for (int p4 = 0; p4 < 16; ++p4) {
      uint4 u4 = hup4[p4];
      g0 = dot2u(wh[0][4 * p4],     u4.x, g0);
      g1 = dot2u(wh[1][4 * p4],     u4.x, g1);
      g2 = dot2u(wh[2][4 * p4],     u4.x, g2);
      g0 = dot2u(wh[0][4 * p4 + 1], u4.y, g0);
      g1 = dot2u(wh[1][4 * p4 + 1], u4.y, g1);
      g2 = dot2u(wh[2][4 * p4 + 1], u4.y, g2);
      g0 = dot2u(wh[0][4 * p4 + 2], u4.z, g0);
      g1 = dot2u(wh[1][4 * p4 + 2], u4.z, g1);
      g2 = dot2u(wh[2][4 * p4 + 2], u4.z, g2);
      g0 = dot2u(wh[0][4 * p4 + 3], u4.w, g0);
      g1 = dot2u(wh[1][4 * p4 + 3], u4.w, g1);
      g2 = dot2u(wh[2][4 * p4 + 3], u4.w, g2);
    }
    __syncthreads();  // b2  (z visible)

    // ---- phase C: gi_z, pair-reduce, gates ----
    float q0 = 0.0f, q1 = 0.0f, q2 = 0.0f;
    #pragma unroll
    for (int p = 0; p < 8; ++p) {
      int pz = half * 8 + p;
      int swz = pz ^ zswz;
      uint32_t u = zu[pz];
      q0 = dot2u(wzl[(hrow)       * 16 + swz], u, q0);
      q1 = dot2u(wzl[(hrow + 256) * 16 + swz], u, q1);
      q2 = dot2u(wzl[(hrow + 512) * 16 + swz], u, q2);
    }
    g0 += __shfl_xor(g0, 1); g1 += __shfl_xor(g1, 1); g2 += __shfl_xor(g2, 1);
    q0 += __shfl_xor(q0, 1); q1 += __shfl_xor(q1, 1); q2 += __shfl_xor(q2, 1);

    float r  = sigm(pf_g0 + q0 + g0);
    float uu = sigm(pf_g1 + q1 + g1);
    float n  = tanh_f(pf_g2 + q2 + r * (g2 + bhn));
    hm = (1.0f - uu) * n + uu * hm;
    if (!half) hf[nxt][hrow] = (f16)hm;

    // ---- prefetch streams for tl+1 ----
    int tn = (tl + 1 < Tlen) ? tl + 1 : tl;
    const f16* gp = gix + ((size_t)tn * NB + b) * 768;
    pf_g0 = (float)gp[hrow]; pf_g1 = (float)gp[hrow + 256]; pf_g2 = (float)gp[hrow + 512];
    if (tid < 32) {
      const f16* zp = zx + ((size_t)tn * NB + b) * 64;
      pf_zm = (float)zp[tid]; pf_zl = (float)zp[32 + tid];
      pf_ep = eps[((size_t)(t0 + tn) * NB + b) * 32 + tid];
    }
    __syncthreads();  // b3  (h_new visible, streams in flight)
  }

  if (!half) {
    if (last) out[b * 256 + hrow] = hm;
    else      hws[b * 256 + hrow] = hm;
  }
}

extern "C" void kernel_launch(void* const* d_in, const int* in_sizes, int n_in,
                              void* d_out, int out_size, void* d_ws, size_t ws_size,
                              hipStream_t stream) {
  const float* x    = (const float*)d_in[0];
  const float* eps  = (const float*)d_in[1];
  const float* emW  = (const float*)d_in[2];
  const float* emb  = (const float*)d_in[3];
  const float* esW  = (const float*)d_in[4];
  const float* esb  = (const float*)d_in[5];
  const float* W_ih = (const float*)d_in[10];
  const float* W_hh = (const float*)d_in[11];
  const float* b_ih = (const float*)d_in[12];
  const float* b_hh = (const float*)d_in[13];
  float* out = (float*)d_out;

  const size_t hbytes = (size_t)NB * 256 * 4;
  int Tc = TSEQ;
  while (Tc > 8 && hbytes + (size_t)Tc * NB * (768 + 64) * 2 > ws_size) Tc >>= 1;

  float* hws = (float*)d_ws;
  f16* gix = (f16*)((char*)d_ws + hbytes);
  f16* zx  = gix + (size_t)Tc * NB * 768;

  int nch = TSEQ / Tc;
  int TT  = Tc < 64 ? Tc : 64;
  int nTT = Tc / TT;

  for (int c = 0; c < nch; ++c) {
    vrnn_pre<<<dim3(NB * nTT), dim3(256), 0, stream>>>(
        x, W_ih, b_ih, b_hh, emW, emb, esW, esb, gix, zx, c * Tc, TT, nTT);
    vrnn_rec<<<dim3(NB), dim3(512), 0, stream>>>(
        gix, zx, eps, W_hh, W_ih, emW, esW, b_hh, hws, out,
        c * Tc, Tc, c == 0 ? 1 : 0, c == nch - 1 ? 1 : 0);
  }
}

// Round 8
// 15764.508 us; speedup vs baseline: 1.3984x; 1.3984x over previous
//
#include <hip/hip_runtime.h>
#include <stdint.h>

#define NB 256      // batch
#define TSEQ 1024   // sequence length
#define TT_MAX 64

typedef _Float16 f16;
typedef _Float16 h2 __attribute__((ext_vector_type(2)));

static __device__ __forceinline__ uint32_t pkh2(float a, float b) {
  h2 v; v[0] = (f16)a; v[1] = (f16)b;
  return __builtin_bit_cast(uint32_t, v);
}

#if __has_builtin(__builtin_amdgcn_fdot2)
static __device__ __forceinline__ float dot2u(uint32_t w, uint32_t h, float c) {
  return __builtin_amdgcn_fdot2(__builtin_bit_cast(h2, w), __builtin_bit_cast(h2, h), c, false);
}
#else
static __device__ __forceinline__ float dot2u(uint32_t w, uint32_t h, float c) {
  h2 a = __builtin_bit_cast(h2, w), b = __builtin_bit_cast(h2, h);
  return c + (float)a[0] * (float)b[0] + (float)a[1] * (float)b[1];
}
#endif

#if __has_builtin(__builtin_amdgcn_rcpf)
#define RCPF(x) __builtin_amdgcn_rcpf(x)
#else
#define RCPF(x) (1.0f / (x))
#endif

static __device__ __forceinline__ float sigm(float x) {
  return RCPF(1.0f + exp2f(-1.44269504f * x));
}
static __device__ __forceinline__ float tanh_f(float x) {
  return 1.0f - 2.0f * RCPF(1.0f + exp2f(2.88539008f * x));
}

// ---------------------------------------------------------------------------
// Precompute kernel (unchanged): gi_x'[t][b][768], zx'[t][b][64]
// ---------------------------------------------------------------------------
__global__ __launch_bounds__(256, 2) void vrnn_pre(
    const float* __restrict__ x, const float* __restrict__ W_ih,
    const float* __restrict__ b_ih, const float* __restrict__ b_hh,
    const float* __restrict__ emW, const float* __restrict__ emb,
    const float* __restrict__ esW, const float* __restrict__ esb,
    f16* __restrict__ gix, f16* __restrict__ zx,
    int chunk_t0, int TT, int nTT)
{
  const int tid = threadIdx.x;
  const int b  = blockIdx.x / nTT;
  const int tt = blockIdx.x % nTT;
  const int tloc0 = tt * TT;

  uint32_t wx[3][32];
  float bias[3];
  #pragma unroll
  for (int rr = 0; rr < 3; ++rr) {
    int j = tid + rr * 256;
    const float4* wr = (const float4*)(W_ih + (size_t)j * 96);
    #pragma unroll
    for (int p4 = 0; p4 < 16; ++p4) {
      float4 v = wr[p4];
      wx[rr][2 * p4]     = pkh2(v.x, v.y);
      wx[rr][2 * p4 + 1] = pkh2(v.z, v.w);
    }
    bias[rr] = b_ih[j] + (rr < 2 ? b_hh[j] : 0.0f);  // fold b_hh into r,z rows only
  }
  uint32_t we[32]; float ebias = 0.0f;
  if (tid < 64) {
    const float* src = (tid < 32) ? (emW + (size_t)tid * 320)
                                  : (esW + (size_t)(tid - 32) * 320);
    #pragma unroll
    for (int p = 0; p < 32; ++p) we[p] = pkh2(src[2 * p], src[2 * p + 1]);
    ebias = (tid < 32) ? emb[tid] : esb[tid - 32];
  }

  __shared__ uint32_t xs[TT_MAX * 32];
  for (int idx = tid; idx < TT * 32; idx += 256) {
    int tl = idx >> 5, pk = idx & 31;
    size_t base = ((size_t)b * TSEQ + (chunk_t0 + tloc0 + tl)) * 64 + 2 * pk;
    xs[idx] = pkh2(x[base], x[base + 1]);
  }
  __syncthreads();

  for (int tl = 0; tl < TT; ++tl) {
    float a0 = bias[0], a1 = bias[1], a2 = bias[2];
    #pragma unroll
    for (int p = 0; p < 32; ++p) {
      uint32_t u = xs[tl * 32 + p];
      a0 = dot2u(wx[0][p], u, a0);
      a1 = dot2u(wx[1][p], u, a1);
      a2 = dot2u(wx[2][p], u, a2);
    }
    size_t ob = (size_t)(tloc0 + tl) * NB + b;
    f16* g = gix + ob * 768;
    g[tid] = (f16)a0; g[tid + 256] = (f16)a1; g[tid + 512] = (f16)a2;
    if (tid < 64) {
      float a3 = ebias;
      #pragma unroll
      for (int p = 0; p < 32; ++p) a3 = dot2u(we[p], xs[tl * 32 + p], a3);
      zx[ob * 64 + tid] = (f16)a3;
    }
  }
}

// ---------------------------------------------------------------------------
// Recurrent kernel v3: 1024 threads (16 waves), one block per batch element.
// R1/R6 post-mortem: hipcc pins an 8-wave block to a 128-VGPR budget no
// matter what __launch_bounds__ says -> the 192-VGPR W_hh array spilled to
// scratch (VALUBusy 5%, 4.4 GB HBM/dispatch). Fix: 4-way k-split so weights
// = 96 VGPRs/thread; total demand ~125 <= 128 budget. Quarter q owns uint4
// blocks j = q + 4*p4 (interleaved) so the 4 quarters' ds_read_b128 of h hit
// disjoint bank groups (contiguous quarters would alias: q*128B % 32banks=0).
// ---------------------------------------------------------------------------
__global__ __attribute__((amdgpu_flat_work_group_size(1024, 1024), amdgpu_waves_per_eu(4)))
void vrnn_rec(
    const f16* __restrict__ gix, const f16* __restrict__ zx,
    const float* __restrict__ eps,
    const float* __restrict__ W_hh, const float* __restrict__ W_ih,
    const float* __restrict__ emW, const float* __restrict__ esW,
    const float* __restrict__ b_hh,
    float* __restrict__ hws, float* __restrict__ out,
    int t0, int Tlen, int first, int last)
{
  const int tid  = threadIdx.x;
  const int b    = blockIdx.x;
  const int hrow = tid >> 2;      // 0..255 : hidden index / gate-row base
  const int q    = tid & 3;       // k-quarter (interleaved uint4 blocks)

  // ---- W_hh quarter rows in registers: 3 x 32 packed f16 pairs = 96 VGPRs ----
  // Quarter q owns uint4 blocks j = q + 4*p4 (p4=0..7), i.e. f16 k in [8j,8j+8).
  uint32_t wh[3][32];
  #pragma unroll
  for (int rr = 0; rr < 3; ++rr) {
    const float* rowp = W_hh + (size_t)(hrow + rr * 256) * 256;
    #pragma unroll
    for (int p4 = 0; p4 < 8; ++p4) {
      int j = q + 4 * p4;
      const float4* wp = (const float4*)(rowp + 8 * j);
      float4 v0 = wp[0], v1 = wp[1];
      wh[rr][4 * p4]     = pkh2(v0.x, v0.y);
      wh[rr][4 * p4 + 1] = pkh2(v0.z, v0.w);
      wh[rr][4 * p4 + 2] = pkh2(v1.x, v1.y);
      wh[rr][4 * p4 + 3] = pkh2(v1.z, v1.w);
    }
  }
  const float bhn = b_hh[512 + hrow];   // n-gate hidden bias (inside r*(h_n+b))

  // ---- LDS ----
  __shared__ uint32_t wzl[768 * 16];     // 48 KB, z-part of W_ih, XOR-swizzled
  __shared__ uint32_t encw[64 * 128];    // 32 KB, enc h-part, rotation-swizzled
  __shared__ __align__(16) f16 hf[2][256];
  __shared__ float encp[1024];
  __shared__ uint32_t zu[16];

  for (int idx = tid; idx < 768 * 16; idx += 1024) {
    int j = idx >> 4, pz = idx & 15;
    wzl[j * 16 + (pz ^ (j & 15))] = pkh2(W_ih[(size_t)j * 96 + 64 + 2 * pz],
                                         W_ih[(size_t)j * 96 + 64 + 2 * pz + 1]);
  }
  for (int idx = tid; idx < 64 * 128; idx += 1024) {
    int row = idx >> 7, pc = idx & 127;
    const float* src = (row < 32) ? (emW + (size_t)row * 320 + 64)
                                  : (esW + (size_t)(row - 32) * 320 + 64);
    encw[(row << 7) + ((pc + row) & 127)] = pkh2(src[2 * pc], src[2 * pc + 1]);
  }

  float hm = 0.0f;
  if (q == 0) {
    hm = first ? 0.0f : hws[b * 256 + hrow];
    hf[0][hrow] = (f16)hm;
  }
  __syncthreads();

  // ---- stream prefetch for t=0 ----
  float pf_g0 = 0.0f, pf_g1 = 0.0f, pf_g2 = 0.0f;
  if (q == 0) {
    const f16* gp0 = gix + (size_t)b * 768;
    pf_g0 = (float)gp0[hrow]; pf_g1 = (float)gp0[hrow + 256]; pf_g2 = (float)gp0[hrow + 512];
  }
  float pf_zm = 0.0f, pf_zl = 0.0f, pf_ep = 0.0f;
  if (tid < 32) {
    const f16* zp = zx + (size_t)b * 64;
    pf_zm = (float)zp[tid]; pf_zl = (float)zp[32 + tid];
    pf_ep = eps[((size_t)t0 * NB + b) * 32 + tid];
  }

  const int erow = tid & 63, eq = tid >> 6;      // enc partials: 16 groups x 8 k-pairs
  const uint32_t* encw_r = encw + (erow << 7);
  const int zswz = hrow & 15;

  for (int tl = 0; tl < Tlen; ++tl) {
    const int cur = tl & 1, nxt = cur ^ 1;
    const uint32_t* hu = (const uint32_t*)&hf[cur][0];

    // ---- phase A: encoder h-part partials (8 k-pairs per thread) ----
    float epacc = 0.0f;
    #pragma unroll
    for (int p = 0; p < 8; ++p) {
      int pc = eq * 8 + p;
      epacc = dot2u(encw_r[(pc + erow) & 127], hu[pc], epacc);
    }
    encp[tid] = epacc;
    __syncthreads();  // b1

    // ---- phase B: z (32 threads) || gh (all threads) ----
    if (tid < 32) {
      float mu = pf_zm, lv = pf_zl;
      #pragma unroll
      for (int qq = 0; qq < 16; ++qq) {
        mu += encp[qq * 64 + tid];
        lv += encp[qq * 64 + 32 + tid];
      }
      float z = mu + pf_ep * exp2f(0.72134752f * lv);   // mu + eps*exp(0.5*lv)
      ((f16*)zu)[tid] = (f16)z;
    }
    // gh: 8 x ds_read_b128 (bank-disjoint across quarters) + 96 dot2
    const uint4* hu4 = (const uint4*)hu;
    float g0 = 0.0f, g1 = 0.0f, g2 = 0.0f;
    #pragma unroll
    for (int p4 = 0; p4 < 8; ++p4) {
      uint4 u4 = hu4[q + 4 * p4];
      g0 = dot2u(wh[0][4 * p4],     u4.x, g0);
      g1 = dot2u(wh[1][4 * p4],     u4.x, g1);
      g2 = dot2u(wh[2][4 * p4],     u4.x, g2);
      g0 = dot2u(wh[0][4 * p4 + 1], u4.y, g0);
      g1 = dot2u(wh[1][4 * p4 + 1], u4.y, g1);
      g2 = dot2u(wh[2][4 * p4 + 1], u4.y, g2);
      g0 = dot2u(wh[0][4 * p4 + 2], u4.z, g0);
      g1 = dot2u(wh[1][4 * p4 + 2], u4.z, g1);
      g2 = dot2u(wh[2][4 * p4 + 2], u4.z, g2);
      g0 = dot2u(wh[0][4 * p4 + 3], u4.w, g0);
      g1 = dot2u(wh[1][4 * p4 + 3], u4.w, g1);
      g2 = dot2u(wh[2][4 * p4 + 3], u4.w, g2);
    }
    __syncthreads();  // b2  (z visible)

    // ---- phase C: gi_z (4 packed k per quarter), 4-lane reduce, gates ----
    float q0 = 0.0f, q1 = 0.0f, q2 = 0.0f;
    #pragma unroll
    for (int p = 0; p < 4; ++p) {
      int pz = q * 4 + p;
      int swz = pz ^ zswz;
      uint32_t u = zu[pz];
      q0 = dot2u(wzl[(hrow)       * 16 + swz], u, q0);
      q1 = dot2u(wzl[(hrow + 256) * 16 + swz], u, q1);
      q2 = dot2u(wzl[(hrow + 512) * 16 + swz], u, q2);
    }
    // r,u gates: fold z-part in (sigmoid of total sum). n gate: keep the
    // z-part separate (it must NOT be scaled by r).
    g0 += q0; g1 += q1; g2 += q2;
    g0 += __shfl_xor(g0, 1); g0 += __shfl_xor(g0, 2);
    g1 += __shfl_xor(g1, 1); g1 += __shfl_xor(g1, 2);
    g2 += __shfl_xor(g2, 1); g2 += __shfl_xor(g2, 2);
    float z_n = q2 + __shfl_xor(q2, 1);
    z_n += __shfl_xor(z_n, 2);       // full z-part of n row
    float n_h = g2 - z_n;            // pure W_hh_n @ h

    if (q == 0) {
      float r  = sigm(pf_g0 + g0);
      float uu = sigm(pf_g1 + g1);
      float n  = tanh_f(pf_g2 + z_n + r * (n_h + bhn));
      hm = (1.0f - uu) * n + uu * hm;
      hf[nxt][hrow] = (f16)hm;
    }

    // ---- prefetch streams for tl+1 ----
    int tn = (tl + 1 < Tlen) ? tl + 1 : tl;
    if (q == 0) {
      const f16* gp = gix + ((size_t)tn * NB + b) * 768;
      pf_g0 = (float)gp[hrow]; pf_g1 = (float)gp[hrow + 256]; pf_g2 = (float)gp[hrow + 512];
    }
    if (tid < 32) {
      const f16* zp = zx + ((size_t)tn * NB + b) * 64;
      pf_zm = (float)zp[tid]; pf_zl = (float)zp[32 + tid];
      pf_ep = eps[((size_t)(t0 + tn) * NB + b) * 32 + tid];
    }
    __syncthreads();  // b3  (h_new visible, streams in flight)
  }

  if (q == 0) {
    if (last) out[b * 256 + hrow] = hm;
    else      hws[b * 256 + hrow] = hm;
  }
}

extern "C" void kernel_launch(void* const* d_in, const int* in_sizes, int n_in,
                              void* d_out, int out_size, void* d_ws, size_t ws_size,
                              hipStream_t stream) {
  const float* x    = (const float*)d_in[0];
  const float* eps  = (const float*)d_in[1];
  const float* emW  = (const float*)d_in[2];
  const float* emb  = (const float*)d_in[3];
  const float* esW  = (const float*)d_in[4];
  const float* esb  = (const float*)d_in[5];
  const float* W_ih = (const float*)d_in[10];
  const float* W_hh = (const float*)d_in[11];
  const float* b_ih = (const float*)d_in[12];
  const float* b_hh = (const float*)d_in[13];
  float* out = (float*)d_out;

  const size_t hbytes = (size_t)NB * 256 * 4;
  int Tc = TSEQ;
  while (Tc > 8 && hbytes + (size_t)Tc * NB * (768 + 64) * 2 > ws_size) Tc >>= 1;

  float* hws = (float*)d_ws;
  f16* gix = (f16*)((char*)d_ws + hbytes);
  f16* zx  = gix + (size_t)Tc * NB * 768;

  int nch = TSEQ / Tc;
  int TT  = Tc < 64 ? Tc : 64;
  int nTT = Tc / TT;

  for (int c = 0; c < nch; ++c) {
    vrnn_pre<<<dim3(NB * nTT), dim3(256), 0, stream>>>(
        x, W_ih, b_ih, b_hh, emW, emb, esW, esb, gix, zx, c * Tc, TT, nTT);
    vrnn_rec<<<dim3(NB), dim3(1024), 0, stream>>>(
        gix, zx, eps, W_hh, W_ih, emW, esW, b_hh, hws, out,
        c * Tc, Tc, c == 0 ? 1 : 0, c == nch - 1 ? 1 : 0);
  }
}